// Round 1
// baseline (2391.286 us; speedup 1.0000x reference)
//
#include <hip/hip_runtime.h>

#define DI __device__ __forceinline__

typedef __attribute__((ext_vector_type(8))) short v8s;
typedef __attribute__((ext_vector_type(4))) short v4s;
typedef __attribute__((ext_vector_type(4))) float v4f;

constexpr int BB = 16, NN = 4096, CH = 64, SS = 1024, KK = 32, DD = 128;
constexpr int LDW = 136;                 // LDS row stride in shorts (pad: 16B-aligned rows, <=2-way banks)
constexpr int GPC = 2;                   // groups per chunk in gemm passes
constexpr int NCHUNK = (BB * SS) / GPC;  // 8192
constexpr int GGRID = 512;

// ---- ws layout (bytes) ----
constexpr size_t OFF_FPSIDX = 0;         // int[16384]
constexpr size_t OFF_KNN    = 65536;     // int[524288]
constexpr size_t OFF_MEAN   = 2162688;   // float[1048576]
constexpr size_t OFF_VARB   = 6356992;   // float[1024]
constexpr size_t OFF_BINS1  = 6361088;   // float[16384]  [64][128][2]
constexpr size_t OFF_BINS2  = 6426624;   // float[16384]
constexpr size_t OFF_RSTD   = 6492160;   // float[16]
constexpr size_t OFF_COEF1  = 6492224;   // float[256]
constexpr size_t OFF_COEF2  = 6493248;   // float[256]
constexpr size_t OFF_W1BF   = 6494272;   // short[16384]
constexpr size_t OFF_W2BF   = 6527040;   // short[16384]
constexpr size_t OFF_XYZT   = 6559808;   // float[196608]  [B][3][N]
constexpr size_t MEMSET_OFF = OFF_VARB;
constexpr size_t MEMSET_LEN = 4096 + 65536 + 65536;

DI short f2bf(float f) {
  unsigned u = __float_as_uint(f);
  u = (u + 0x7fffu + ((u >> 16) & 1u)) >> 16;
  return (short)u;
}
DI float bf2f(short s) { return __uint_as_float(((unsigned)(unsigned short)s) << 16); }

// ---------------- xyz transpose: [B][N][3] -> [B][3][N] ----------------
__global__ void xpose_kernel(const float* __restrict__ xyz, float* __restrict__ xyzT) {
  int i = blockIdx.x * 256 + threadIdx.x;  // < B*N
  int b = i >> 12, n = i & 4095;
  const float* s = xyz + (size_t)i * 3;
  float* d = xyzT + (size_t)b * 3 * NN + n;
  d[0] = s[0]; d[NN] = s[1]; d[2 * NN] = s[2];
}

// ---------------- weight f32 -> bf16 ----------------
__global__ void cvtw_kernel(const float* __restrict__ w1, const float* __restrict__ w2,
                            short* __restrict__ w1b, short* __restrict__ w2b) {
  int i = blockIdx.x * 256 + threadIdx.x;  // < 16384
  w1b[i] = f2bf(w1[i]);
  w2b[i] = f2bf(w2[i]);
}

// ---------------- FPS (exact f64 ordering) ----------------
// one block per batch; 512 threads, 8 points/thread. min_d chain fully f64.
__global__ __launch_bounds__(512) void fps_kernel(const float* __restrict__ xyzT,
                                                  int* __restrict__ fps_idx,
                                                  float* __restrict__ out_xyz) {
  int b = blockIdx.x, t = threadIdx.x;
  const float* bx = xyzT + (size_t)b * 3 * NN;
  const float* by = bx + NN;
  const float* bz = bx + 2 * NN;
  double px[8], py[8], pz[8], mind[8];
#pragma unroll
  for (int p = 0; p < 8; ++p) {
    int i = p * 512 + t;
    px[p] = (double)bx[i]; py[p] = (double)by[i]; pz[p] = (double)bz[i];
    mind[p] = 1e10;
  }
  __shared__ double s_val[2][8];
  __shared__ int s_idx[2][8];
  if (t == 0) {
    fps_idx[b * SS] = 0;
    out_xyz[(size_t)b * SS * 3 + 0] = bx[0];
    out_xyz[(size_t)b * SS * 3 + 1] = by[0];
    out_xyz[(size_t)b * SS * 3 + 2] = bz[0];
  }
  double lx = (double)bx[0], ly = (double)by[0], lz = (double)bz[0];
  for (int j = 1; j < SS; ++j) {
    double bv = -1.0; int bi = 0;
#pragma unroll
    for (int p = 0; p < 8; ++p) {
      double dx = px[p] - lx, dy = py[p] - ly, dz = pz[p] - lz;
      double d = fma(dx, dx, fma(dy, dy, dz * dz));  // exact products: true ordering
      if (d < mind[p]) mind[p] = d;
      if (mind[p] > bv) { bv = mind[p]; bi = p * 512 + t; }
    }
#pragma unroll
    for (int m = 1; m < 64; m <<= 1) {
      double ov = __shfl_xor(bv, m, 64);
      int oi = __shfl_xor(bi, m, 64);
      if (ov > bv || (ov == bv && oi < bi)) { bv = ov; bi = oi; }
    }
    int buf = j & 1;
    if ((t & 63) == 0) { s_val[buf][t >> 6] = bv; s_idx[buf][t >> 6] = bi; }
    __syncthreads();
    double fv = s_val[buf][0]; int fi = s_idx[buf][0];
#pragma unroll
    for (int w = 1; w < 8; ++w) {
      double v = s_val[buf][w]; int i2 = s_idx[buf][w];
      if (v > fv || (v == fv && i2 < fi)) { fv = v; fi = i2; }
    }
    float gx = bx[fi], gy = by[fi], gz = bz[fi];  // uniform broadcast loads
    if (t == 0) {
      fps_idx[b * SS + j] = fi;
      out_xyz[((size_t)b * SS + j) * 3 + 0] = gx;
      out_xyz[((size_t)b * SS + j) * 3 + 1] = gy;
      out_xyz[((size_t)b * SS + j) * 3 + 2] = gz;
    }
    lx = (double)gx; ly = (double)gy; lz = (double)gz;
  }
}

// ---------------- kNN: one wave per query ----------------
// f32 bulk distances -> threshold (32nd smallest of per-lane minima, inflated) ->
// compact candidates to LDS with exact f64 distances -> 32 rounds exact argmin.
__global__ __launch_bounds__(256) void knn_kernel(const float* __restrict__ xyzT,
                                                  const int* __restrict__ fps_idx,
                                                  int* __restrict__ knn_idx) {
  int wave = threadIdx.x >> 6, lane = threadIdx.x & 63;
  int q = blockIdx.x * 4 + wave, b = q >> 10;
  const float* bx = xyzT + (size_t)b * 3 * NN;
  const float* by = bx + NN;
  const float* bz = bx + 2 * NN;
  int qi = fps_idx[q];
  float qx = bx[qi], qy = by[qi], qz = bz[qi];
  float d[64];
  float lmin = 1e30f;
#pragma unroll
  for (int j = 0; j < 64; ++j) {
    int n = j * 64 + lane;
    float dx = bx[n] - qx, dy = by[n] - qy, dz = bz[n] - qz;
    d[j] = fmaf(dx, dx, fmaf(dy, dy, dz * dz));
    lmin = fminf(lmin, d[j]);
  }
  // bitonic sort of per-lane minima across the wave (ascending)
  float v = lmin;
#pragma unroll
  for (int size = 2; size <= 64; size <<= 1) {
#pragma unroll
    for (int stride = size >> 1; stride > 0; stride >>= 1) {
      float o = __shfl_xor(v, stride, 64);
      bool keepmin = (((lane & size) == 0) == ((lane & stride) == 0));
      v = keepmin ? fminf(v, o) : fmaxf(v, o);
    }
  }
  float tau = __shfl(v, 31, 64) * 1.00001f + 1e-20f;  // >= true 32nd smallest, with margin

  __shared__ double cd[4][512];
  __shared__ int ci[4][512];
  int cnt = 0;
#pragma unroll
  for (int j = 0; j < 64; ++j) {
    bool pred = (d[j] <= tau);
    unsigned long long mask = __ballot(pred);
    if (pred) {
      int pos = cnt + __popcll(mask & ((1ull << lane) - 1ull));
      if (pos < 512) {
        int n = j * 64 + lane;
        double dx = (double)bx[n] - (double)qx;
        double dy = (double)by[n] - (double)qy;
        double dz = (double)bz[n] - (double)qz;
        cd[wave][pos] = fma(dx, dx, fma(dy, dy, dz * dz));
        ci[wave][pos] = n;
      }
    }
    cnt += __popcll(mask);
  }
  if (cnt > 512) cnt = 512;
  // 32 exact selection rounds (candidates are stored in ascending-n order; ties -> smaller pos = smaller n)
  for (int r = 0; r < 32; ++r) {
    double bv = 1e300; int bp = 1 << 30;
    for (int p = lane; p < cnt; p += 64) {
      double vv = cd[wave][p];
      if (vv < bv) { bv = vv; bp = p; }
    }
#pragma unroll
    for (int m = 1; m < 64; m <<= 1) {
      double ov = __shfl_xor(bv, m, 64);
      int op = __shfl_xor(bp, m, 64);
      if (ov < bv || (ov == bv && op < bp)) { bv = ov; bp = op; }
    }
    if (bp < (1 << 30) && (bp & 63) == lane) {
      knn_idx[(size_t)q * KK + r] = ci[wave][bp];
      cd[wave][bp] = 1e300;
    }
  }
}

// ---------------- per-group mean over K + per-batch sum of diff^2 ----------------
__global__ __launch_bounds__(256) void meanvar_kernel(const float* __restrict__ points,
                                                      const int* __restrict__ kidx,
                                                      float* __restrict__ mean_out,
                                                      float* __restrict__ var_bins) {
  int wave = threadIdx.x >> 6, lane = threadIdx.x & 63;
  int g = blockIdx.x * 4 + wave;  // global group
  int b = g >> 10;
  const float* pb = points + (size_t)b * NN * CH;
  const int* idx = kidx + (size_t)g * KK;
  float s1 = 0.f, s2 = 0.f;
#pragma unroll
  for (int k = 0; k < KK; ++k) {
    float x = pb[(size_t)idx[k] * CH + lane];
    s1 += x;
    s2 = fmaf(x, x, s2);
  }
  float m = s1 * (1.0f / 32.0f);
  mean_out[(size_t)g * CH + lane] = m;
  float part = s2 - s1 * m;  // sum_k (x-m)^2 (exact algebra: 32*m == s1)
#pragma unroll
  for (int mm = 1; mm < 64; mm <<= 1) part += __shfl_xor(part, mm, 64);
  if (lane == 0) atomicAdd(&var_bins[b * 64 + (g & 63)], part);
}

__global__ void fin_std_kernel(const float* __restrict__ bins, float* __restrict__ rstd) {
  int t = threadIdx.x;
  if (t < BB) {
    float s = 0.f;
    for (int i = 0; i < 64; ++i) s += bins[t * 64 + i];
    float var = s / (float)(SS * KK * CH - 1);
    rstd[t] = 1.0f / (sqrtf(var) + 1e-5f);
  }
}

__global__ void fin_bn_kernel(const float* __restrict__ bins, const float* __restrict__ g,
                              const float* __restrict__ be, float* __restrict__ coef) {
  int o = threadIdx.x;  // < 128
  float s = 0.f, qq = 0.f;
  for (int bin = 0; bin < 64; ++bin) {
    s += bins[(bin * 128 + o) * 2 + 0];
    qq += bins[(bin * 128 + o) * 2 + 1];
  }
  constexpr float invM = 1.0f / (float)(BB * SS * KK);
  float mean = s * invM;
  float var = qq * invM - mean * mean;
  if (var < 0.f) var = 0.f;
  float sc = g[o] / sqrtf(var + 1e-5f);
  coef[2 * o] = sc;
  coef[2 * o + 1] = be[o] - mean * sc;
}

// ---------------- GEMM passes ----------------
// PASS 0: X->h1, accumulate BN1 stats.
// PASS 1: X->h1->P->h2, accumulate BN2 stats.
// PASS 2: X->h1->P->h2, BN2 + residual + lrelu + maxpool -> out.
// Block = 4 waves; chunk = 2 groups. Wave grid 2x2 (o-half x group).
// W fragments in registers (loaded once); Xs/Ps in LDS.
template <int PASS>
__global__ __launch_bounds__(256, 2) void gemm_pass(
    const float* __restrict__ points, const int* __restrict__ kidx, const int* __restrict__ fidx,
    const float* __restrict__ mean, const float* __restrict__ rstd,
    const float* __restrict__ alpha, const float* __restrict__ beta,
    const short* __restrict__ w1bf, const short* __restrict__ w2bf,
    const float* __restrict__ coef1, const float* __restrict__ coef2,
    float* __restrict__ bins_out, float* __restrict__ out_pooled) {
  __shared__ short Xs[GPC * 32 * LDW];
  __shared__ short Ps[(PASS >= 1) ? (GPC * 32 * LDW) : 8];
  __shared__ float sAlpha[64], sBeta[64];
  __shared__ float sCoef1[256], sCoef2[256];
  __shared__ float bnS[128], bnQ[128];

  int tid = threadIdx.x;
  int wave = tid >> 6, lane = tid & 63;
  int q4 = lane >> 4, l15 = lane & 15;
  int ohalf = wave & 1, gsel = wave >> 1;

  // W fragments -> registers
  v8s wf1[4][4];
  v8s wf2[4][4];
#pragma unroll
  for (int ot = 0; ot < 4; ++ot) {
    int row = ohalf * 64 + ot * 16 + l15;
#pragma unroll
    for (int cs = 0; cs < 4; ++cs) {
      wf1[ot][cs] = *(const v8s*)(w1bf + row * 128 + cs * 32 + q4 * 8);
      if constexpr (PASS >= 1) wf2[ot][cs] = *(const v8s*)(w2bf + row * 128 + cs * 32 + q4 * 8);
    }
  }
  if (tid < 64) { sAlpha[tid] = alpha[tid]; sBeta[tid] = beta[tid]; }
  if constexpr (PASS >= 1) sCoef1[tid] = coef1[tid];
  if constexpr (PASS == 2) sCoef2[tid] = coef2[tid];
  if constexpr (PASS <= 1) {
    if (tid < 128) { bnS[tid] = 0.f; bnQ[tid] = 0.f; }
  }
  __syncthreads();

  for (int chunk = blockIdx.x; chunk < NCHUNK; chunk += GGRID) {
    int g0 = chunk * GPC;
    // ---- stage Xs: [g][k][0:64]=normalized grouped, [64:128]=new_pts ----
    {
      int sg = tid >> 7;
      int sk = (tid >> 2) & 31;
      int qr = tid & 3;
      int ggl = g0 + sg;
      int b = ggl >> 10;
      const float* pb = points + (size_t)b * NN * CH;
      int row = (qr < 2) ? kidx[(size_t)ggl * KK + sk] : fidx[ggl];
      int ch0 = (qr & 1) * 32;
      const float* src = pb + (size_t)row * CH + ch0;
      const float* mrow = mean + (size_t)ggl * CH + ch0;
      float rs = rstd[b];
      bool norm = (qr < 2);
      v8s pack[4];
#pragma unroll
      for (int cc = 0; cc < 32; cc += 4) {
        float4 vv = *(const float4*)(src + cc);
        if (norm) {
          float4 mv = *(const float4*)(mrow + cc);
          vv.x = fmaf((vv.x - mv.x) * rs, sAlpha[ch0 + cc + 0], sBeta[ch0 + cc + 0]);
          vv.y = fmaf((vv.y - mv.y) * rs, sAlpha[ch0 + cc + 1], sBeta[ch0 + cc + 1]);
          vv.z = fmaf((vv.z - mv.z) * rs, sAlpha[ch0 + cc + 2], sBeta[ch0 + cc + 2]);
          vv.w = fmaf((vv.w - mv.w) * rs, sAlpha[ch0 + cc + 3], sBeta[ch0 + cc + 3]);
        }
        pack[cc >> 3][(cc & 7) + 0] = f2bf(vv.x);
        pack[cc >> 3][(cc & 7) + 1] = f2bf(vv.y);
        pack[cc >> 3][(cc & 7) + 2] = f2bf(vv.z);
        pack[cc >> 3][(cc & 7) + 3] = f2bf(vv.w);
      }
      short* dst = &Xs[(sg * 32 + sk) * LDW + qr * 32];
#pragma unroll
      for (int p2 = 0; p2 < 4; ++p2) *(v8s*)(dst + p2 * 8) = pack[p2];
    }
    __syncthreads();

    // ---- GEMM1: h1 = W1 * X ----
    v4f acc[4][2] = {};
#pragma unroll
    for (int cs = 0; cs < 4; ++cs) {
      v8s bfr[2];
#pragma unroll
      for (int kt = 0; kt < 2; ++kt)
        bfr[kt] = *(const v8s*)&Xs[(gsel * 32 + kt * 16 + l15) * LDW + cs * 32 + q4 * 8];
#pragma unroll
      for (int ot = 0; ot < 4; ++ot)
#pragma unroll
        for (int kt = 0; kt < 2; ++kt)
          acc[ot][kt] = __builtin_amdgcn_mfma_f32_16x16x32_bf16(wf1[ot][cs], bfr[kt], acc[ot][kt], 0, 0, 0);
    }

    if constexpr (PASS == 0) {
      // BN1 stats of h1
#pragma unroll
      for (int ot = 0; ot < 4; ++ot) {
        float sv[4], sq[4];
#pragma unroll
        for (int r = 0; r < 4; ++r) {
          float a0 = acc[ot][0][r], a1 = acc[ot][1][r];
          sv[r] = a0 + a1;
          sq[r] = fmaf(a0, a0, a1 * a1);
        }
#pragma unroll
        for (int m = 1; m < 16; m <<= 1)
#pragma unroll
          for (int r = 0; r < 4; ++r) {
            sv[r] += __shfl_xor(sv[r], m, 64);
            sq[r] += __shfl_xor(sq[r], m, 64);
          }
        if (l15 == 0) {
          int o0 = ohalf * 64 + ot * 16 + q4 * 4;
#pragma unroll
          for (int r = 0; r < 4; ++r) {
            atomicAdd(&bnS[o0 + r], sv[r]);
            atomicAdd(&bnQ[o0 + r], sq[r]);
          }
        }
      }
    } else {
      // ---- P = lrelu(bn1(h1)) -> Ps ----
#pragma unroll
      for (int ot = 0; ot < 4; ++ot) {
        int o0 = ohalf * 64 + ot * 16 + q4 * 4;
#pragma unroll
        for (int kt = 0; kt < 2; ++kt) {
          v4s pk;
#pragma unroll
          for (int r = 0; r < 4; ++r) {
            float h = fmaf(acc[ot][kt][r], sCoef1[2 * (o0 + r)], sCoef1[2 * (o0 + r) + 1]);
            h = (h >= 0.f) ? h : 0.01f * h;
            pk[r] = f2bf(h);
          }
          *(v4s*)&Ps[(gsel * 32 + kt * 16 + l15) * LDW + o0] = pk;
        }
      }
      __syncthreads();

      // ---- GEMM2: h2 = W2 * P ----
      v4f acc2[4][2] = {};
#pragma unroll
      for (int cs = 0; cs < 4; ++cs) {
        v8s pfr[2];
#pragma unroll
        for (int kt = 0; kt < 2; ++kt)
          pfr[kt] = *(const v8s*)&Ps[(gsel * 32 + kt * 16 + l15) * LDW + cs * 32 + q4 * 8];
#pragma unroll
        for (int ot = 0; ot < 4; ++ot)
#pragma unroll
          for (int kt = 0; kt < 2; ++kt)
            acc2[ot][kt] = __builtin_amdgcn_mfma_f32_16x16x32_bf16(wf2[ot][cs], pfr[kt], acc2[ot][kt], 0, 0, 0);
      }

      if constexpr (PASS == 1) {
        // BN2 stats of h2
#pragma unroll
        for (int ot = 0; ot < 4; ++ot) {
          float sv[4], sq[4];
#pragma unroll
          for (int r = 0; r < 4; ++r) {
            float a0 = acc2[ot][0][r], a1 = acc2[ot][1][r];
            sv[r] = a0 + a1;
            sq[r] = fmaf(a0, a0, a1 * a1);
          }
#pragma unroll
          for (int m = 1; m < 16; m <<= 1)
#pragma unroll
            for (int r = 0; r < 4; ++r) {
              sv[r] += __shfl_xor(sv[r], m, 64);
              sq[r] += __shfl_xor(sq[r], m, 64);
            }
          if (l15 == 0) {
            int o0 = ohalf * 64 + ot * 16 + q4 * 4;
#pragma unroll
            for (int r = 0; r < 4; ++r) {
              atomicAdd(&bnS[o0 + r], sv[r]);
              atomicAdd(&bnQ[o0 + r], sq[r]);
            }
          }
        }
      } else {
        // ---- epilogue: lrelu(bn2(h2) + X) , max over k, store ----
#pragma unroll
        for (int ot = 0; ot < 4; ++ot) {
          int o0 = ohalf * 64 + ot * 16 + q4 * 4;
          float mx[4] = {-1e30f, -1e30f, -1e30f, -1e30f};
#pragma unroll
          for (int kt = 0; kt < 2; ++kt) {
            v4s xv = *(const v4s*)&Xs[(gsel * 32 + kt * 16 + l15) * LDW + o0];
#pragma unroll
            for (int r = 0; r < 4; ++r) {
              float h = fmaf(acc2[ot][kt][r], sCoef2[2 * (o0 + r)], sCoef2[2 * (o0 + r) + 1]);
              float val = h + bf2f(xv[r]);
              val = (val >= 0.f) ? val : 0.01f * val;
              mx[r] = fmaxf(mx[r], val);
            }
          }
#pragma unroll
          for (int m = 1; m < 16; m <<= 1)
#pragma unroll
            for (int r = 0; r < 4; ++r) mx[r] = fmaxf(mx[r], __shfl_xor(mx[r], m, 64));
          if (l15 == 0) {
            float4 o4;
            o4.x = mx[0]; o4.y = mx[1]; o4.z = mx[2]; o4.w = mx[3];
            *(float4*)(out_pooled + (size_t)(g0 + gsel) * DD + o0) = o4;
          }
        }
      }
    }
    __syncthreads();
  }

  if constexpr (PASS <= 1) {
    if (tid < 128) {
      float* bb = bins_out + (((blockIdx.x & 63) * 128 + tid) << 1);
      atomicAdd(bb, bnS[tid]);
      atomicAdd(bb + 1, bnQ[tid]);
    }
  }
}

extern "C" void kernel_launch(void* const* d_in, const int* in_sizes, int n_in,
                              void* d_out, int out_size, void* d_ws, size_t ws_size,
                              hipStream_t stream) {
  const float* xyz    = (const float*)d_in[0];
  const float* points = (const float*)d_in[1];
  const float* alpha  = (const float*)d_in[2];
  const float* beta   = (const float*)d_in[3];
  const float* w1     = (const float*)d_in[4];
  const float* g1     = (const float*)d_in[6];
  const float* be1    = (const float*)d_in[7];
  const float* w2     = (const float*)d_in[8];
  const float* g2     = (const float*)d_in[10];
  const float* be2    = (const float*)d_in[11];
  float* out = (float*)d_out;

  char* w = (char*)d_ws;
  int* fps_i   = (int*)(w + OFF_FPSIDX);
  int* knn_i   = (int*)(w + OFF_KNN);
  float* meanp = (float*)(w + OFF_MEAN);
  float* varb  = (float*)(w + OFF_VARB);
  float* bins1 = (float*)(w + OFF_BINS1);
  float* bins2 = (float*)(w + OFF_BINS2);
  float* rstdp = (float*)(w + OFF_RSTD);
  float* coef1 = (float*)(w + OFF_COEF1);
  float* coef2 = (float*)(w + OFF_COEF2);
  short* w1b   = (short*)(w + OFF_W1BF);
  short* w2b   = (short*)(w + OFF_W2BF);
  float* xyzT  = (float*)(w + OFF_XYZT);

  hipMemsetAsync(w + MEMSET_OFF, 0, MEMSET_LEN, stream);
  xpose_kernel<<<256, 256, 0, stream>>>(xyz, xyzT);
  cvtw_kernel<<<64, 256, 0, stream>>>(w1, w2, w1b, w2b);
  fps_kernel<<<BB, 512, 0, stream>>>(xyzT, fps_i, out);
  knn_kernel<<<(BB * SS) / 4, 256, 0, stream>>>(xyzT, fps_i, knn_i);
  meanvar_kernel<<<(BB * SS) / 4, 256, 0, stream>>>(points, knn_i, meanp, varb);
  fin_std_kernel<<<1, 64, 0, stream>>>(varb, rstdp);
  gemm_pass<0><<<GGRID, 256, 0, stream>>>(points, knn_i, fps_i, meanp, rstdp, alpha, beta,
                                          w1b, w2b, coef1, coef2, bins1, nullptr);
  fin_bn_kernel<<<1, 128, 0, stream>>>(bins1, g1, be1, coef1);
  gemm_pass<1><<<GGRID, 256, 0, stream>>>(points, knn_i, fps_i, meanp, rstdp, alpha, beta,
                                          w1b, w2b, coef1, coef2, bins2, nullptr);
  fin_bn_kernel<<<1, 128, 0, stream>>>(bins2, g2, be2, coef2);
  gemm_pass<2><<<GGRID, 256, 0, stream>>>(points, knn_i, fps_i, meanp, rstdp, alpha, beta,
                                          w1b, w2b, coef1, coef2, nullptr, out + (size_t)BB * SS * 3);
}